// Round 1
// baseline (107.671 us; speedup 1.0000x reference)
//
#include <hip/hip_runtime.h>

#define NSUB   10000
#define NCLS   17
#define NG     500
#define NE     80000
#define HIDN   8
#define CWLD   52          // 0..16 = 1/Var, 17..33 = Mu/Var, 34..41 = W_l, 42..49 = W_r, 50/51 pad
#define NEG_SLOPE 0.2f

// ws layout (in floats)
#define OFF_CW   0                      // NG*CWLD = 26000
#define OFF_D    (OFF_CW + NG*CWLD)     // 32
#define OFF_XL   (OFF_D + 32)           // NSUB*8
#define OFF_XR   (OFF_XL + NSUB*HIDN)   // NSUB*8
#define OFF_LP   (OFF_XR + NSUB*HIDN)   // NSUB*17
#define OFF_E    (OFF_LP + NSUB*NCLS)   // NE
#define OFF_MORD (OFF_E + NE)           // NSUB (uint)
#define OFF_NUM  (OFF_MORD + NSUB)      // NSUB
#define OFF_DEN  (OFF_NUM + NSUB)       // NSUB

// ---------------- prep: build combined weight matrix CW[g][52] and D[c] ----------------
__global__ void k_prep(const float* __restrict__ Mu, const float* __restrict__ Var,
                       const float* __restrict__ Wl, const float* __restrict__ Wr,
                       float* __restrict__ CW, float* __restrict__ D) {
    const int b = blockIdx.x;
    if (b < 2) {
        const int g = b * 256 + threadIdx.x;
        if (g < NG) {
            float* row = CW + g * CWLD;
            #pragma unroll
            for (int c = 0; c < NCLS; c++) {
                const float iv = 1.0f / Var[c * NG + g];
                row[c]        = iv;
                row[NCLS + c] = Mu[c * NG + g] * iv;
            }
            #pragma unroll
            for (int h = 0; h < HIDN; h++) {
                row[34 + h] = Wl[g * HIDN + h];
                row[42 + h] = Wr[g * HIDN + h];
            }
            row[50] = 0.f; row[51] = 0.f;
        }
    } else {
        const int c = b - 2;           // 17 classes
        float s = 0.f;
        for (int g = threadIdx.x; g < NG; g += 256) {
            const float m = Mu[c * NG + g];
            s += m * m / Var[c * NG + g];
        }
        __shared__ float red[4];
        #pragma unroll
        for (int o = 32; o; o >>= 1) s += __shfl_xor(s, o);
        const int w = threadIdx.x >> 6, l = threadIdx.x & 63;
        if (l == 0) red[w] = s;
        __syncthreads();
        if (threadIdx.x == 0) D[c] = red[0] + red[1] + red[2] + red[3];
    }
}

// ---------------- per-cell: fused GEMM + softmax + ll_prot + xl/xr + logP ----------------
__launch_bounds__(512)
__global__ void k_cell(const float* __restrict__ x, const int* __restrict__ sidx,
                       const float* __restrict__ Wp, const float* __restrict__ Sp,
                       const float* __restrict__ bl, const float* __restrict__ br,
                       const float* __restrict__ CW, const float* __restrict__ D,
                       float* __restrict__ out, float* __restrict__ XL,
                       float* __restrict__ XR, float* __restrict__ LP) {
    const int w = threadIdx.x >> 6, l = threadIdx.x & 63;
    const int cell = blockIdx.x * 64 + l;

    float acc[50];
    #pragma unroll
    for (int i = 0; i < 50; i++) acc[i] = 0.f;

    const int g0 = w * 64;
    const int g1 = (w == 7) ? NG : (g0 + 64);

    if (cell < NSUB) {
        const float* xrow = x + (size_t)cell * NG;
        for (int g = g0; g < g1; g += 4) {
            const float4 xv = *reinterpret_cast<const float4*>(xrow + g);
            const float* cw = CW + g * CWLD;          // wave-uniform address
            #pragma unroll
            for (int j = 0; j < 4; j++) {
                const float xs = (&xv.x)[j];
                const float x2 = xs * xs;
                const float* c2 = cw + j * CWLD;
                #pragma unroll
                for (int c = 0; c < NCLS; c++) acc[c] += x2 * c2[c];
                #pragma unroll
                for (int c = 0; c < NCLS; c++) acc[NCLS + c] += xs * c2[NCLS + c];
                #pragma unroll
                for (int h = 0; h < 2 * HIDN; h++) acc[34 + h] += xs * c2[34 + h];
            }
        }
    }

    // tree-reduce the 8 waves' partial sums (same lane = same cell)
    __shared__ float lds[4 * 64 * 53];
    if (w >= 4) { float* p = lds + ((w - 4) * 64 + l) * 53;
        #pragma unroll
        for (int i = 0; i < 50; i++) p[i] = acc[i]; }
    __syncthreads();
    if (w < 4)  { const float* p = lds + (w * 64 + l) * 53;
        #pragma unroll
        for (int i = 0; i < 50; i++) acc[i] += p[i]; }
    __syncthreads();
    if (w == 2 || w == 3) { float* p = lds + ((w - 2) * 64 + l) * 53;
        #pragma unroll
        for (int i = 0; i < 50; i++) p[i] = acc[i]; }
    __syncthreads();
    if (w < 2)  { const float* p = lds + (w * 64 + l) * 53;
        #pragma unroll
        for (int i = 0; i < 50; i++) acc[i] += p[i]; }
    __syncthreads();
    if (w == 1) { float* p = lds + l * 53;
        #pragma unroll
        for (int i = 0; i < 50; i++) p[i] = acc[i]; }
    __syncthreads();

    if (w == 0) {
        float ll = 0.f;
        if (cell < NSUB) {
            const float* p2 = lds + l * 53;
            #pragma unroll
            for (int i = 0; i < 50; i++) acc[i] += p2[i];

            const int idx = sidx[cell];
            const float* wrow = Wp + (size_t)idx * NCLS;
            float p[NCLS];
            float mx = -1e30f;
            #pragma unroll
            for (int c = 0; c < NCLS; c++) { p[c] = wrow[c]; mx = fmaxf(mx, p[c]); }
            float sum = 0.f;
            #pragma unroll
            for (int c = 0; c < NCLS; c++) { p[c] = __expf(p[c] - mx); sum += p[c]; }
            const float inv = 1.0f / sum;
            const float s = Sp[idx];
            float* orow = out + 2 + (size_t)cell * NCLS;
            float* lrow = LP + (size_t)cell * NCLS;
            #pragma unroll
            for (int c = 0; c < NCLS; c++) {
                p[c] *= inv;
                orow[c] = p[c];
                lrow[c] = __logf(p[c] + 1e-8f);
                const float F = -0.5f * acc[c] + s * acc[NCLS + c] - 0.5f * s * s * D[c];
                ll += p[c] * F;
            }
            #pragma unroll
            for (int h = 0; h < HIDN; h++) {
                XL[cell * HIDN + h] = acc[34 + h] + bl[h];
                XR[cell * HIDN + h] = acc[42 + h] + br[h];
            }
        }
        #pragma unroll
        for (int o = 32; o; o >>= 1) ll += __shfl_xor(ll, o);
        if (l == 0) atomicAdd(out, ll * (1.0f / NSUB));
    }
}

// ---------------- edge pass 1: e_k and segment max over dst ----------------
__device__ __forceinline__ unsigned f2ord(float f) {
    unsigned u = __float_as_uint(f);
    return (u & 0x80000000u) ? ~u : (u | 0x80000000u);
}
__device__ __forceinline__ float ord2f(unsigned o) {
    unsigned u = (o & 0x80000000u) ? (o ^ 0x80000000u) : ~o;
    return __uint_as_float(u);
}

__global__ void k_edge1(const int* __restrict__ ei, const float* __restrict__ XL,
                        const float* __restrict__ XR, const float* __restrict__ att,
                        float* __restrict__ E, unsigned* __restrict__ MORD) {
    const int k = blockIdx.x * 256 + threadIdx.x;
    if (k >= NE) return;
    const int s = ei[k], d = ei[NE + k];
    const float4 a0 = *reinterpret_cast<const float4*>(XL + s * HIDN);
    const float4 a1 = *reinterpret_cast<const float4*>(XL + s * HIDN + 4);
    const float4 b0 = *reinterpret_cast<const float4*>(XR + d * HIDN);
    const float4 b1 = *reinterpret_cast<const float4*>(XR + d * HIDN + 4);
    float hv[8] = { a0.x + b0.x, a0.y + b0.y, a0.z + b0.z, a0.w + b0.w,
                    a1.x + b1.x, a1.y + b1.y, a1.z + b1.z, a1.w + b1.w };
    float e = 0.f;
    #pragma unroll
    for (int h = 0; h < HIDN; h++) {
        float v = hv[h];
        v = (v > 0.f) ? v : NEG_SLOPE * v;
        e += v * att[h];
    }
    E[k] = e;
    atomicMax(MORD + d, f2ord(e));
}

// ---------------- edge pass 2: exp + weighted accumulation ----------------
__global__ void k_edge2(const int* __restrict__ ei, const float* __restrict__ out,
                        const float* __restrict__ LP, const float* __restrict__ E,
                        const unsigned* __restrict__ MORD,
                        float* __restrict__ NUM, float* __restrict__ DEN) {
    const int k = blockIdx.x * 256 + threadIdx.x;
    if (k >= NE) return;
    const int s = ei[k], d = ei[NE + k];
    const float m = ord2f(MORD[d]);
    const float ex = __expf(E[k] - m);
    const float* Ps = out + 2 + (size_t)s * NCLS;
    const float* Ld = LP + (size_t)d * NCLS;
    float wgt = 0.f;
    #pragma unroll
    for (int c = 0; c < NCLS; c++) wgt += Ps[c] * Ld[c];
    atomicAdd(NUM + d, ex * wgt);
    atomicAdd(DEN + d, ex);
}

// ---------------- node pass: ce_space = -sum(num/den)/n ----------------
__global__ void k_node(const float* __restrict__ NUM, const float* __restrict__ DEN,
                       float* __restrict__ out) {
    const int n = blockIdx.x * 256 + threadIdx.x;
    float v = 0.f;
    if (n < NSUB) {
        const float dd = DEN[n];
        if (dd > 0.f) v = NUM[n] / dd;
    }
    #pragma unroll
    for (int o = 32; o; o >>= 1) v += __shfl_xor(v, o);
    if ((threadIdx.x & 63) == 0) atomicAdd(out + 1, -v * (1.0f / NSUB));
}

extern "C" void kernel_launch(void* const* d_in, const int* in_sizes, int n_in,
                              void* d_out, int out_size, void* d_ws, size_t ws_size,
                              hipStream_t stream) {
    const float* x    = (const float*)d_in[0];
    const float* Mu   = (const float*)d_in[1];
    const float* Var  = (const float*)d_in[2];
    const int*   ei   = (const int*)d_in[3];
    const int*   sidx = (const int*)d_in[4];
    const float* Wp   = (const float*)d_in[5];
    const float* Sp   = (const float*)d_in[6];
    const float* Wl   = (const float*)d_in[7];
    const float* bl   = (const float*)d_in[8];
    const float* Wr   = (const float*)d_in[9];
    const float* br   = (const float*)d_in[10];
    const float* att  = (const float*)d_in[11];
    float* out = (float*)d_out;
    float* ws  = (float*)d_ws;

    float*    CW   = ws + OFF_CW;
    float*    D    = ws + OFF_D;
    float*    XL   = ws + OFF_XL;
    float*    XR   = ws + OFF_XR;
    float*    LP   = ws + OFF_LP;
    float*    E    = ws + OFF_E;
    unsigned* MORD = (unsigned*)(ws + OFF_MORD);
    float*    NUM  = ws + OFF_NUM;
    float*    DEN  = ws + OFF_DEN;

    (void)in_sizes; (void)n_in; (void)out_size; (void)ws_size;

    // zero the atomic accumulators (out[0], out[1]) and MORD/NUM/DEN (contiguous)
    hipMemsetAsync(out, 0, 2 * sizeof(float), stream);
    hipMemsetAsync(ws + OFF_MORD, 0, 3 * NSUB * sizeof(float), stream);

    k_prep<<<19, 256, 0, stream>>>(Mu, Var, Wl, Wr, CW, D);
    k_cell<<<(NSUB + 63) / 64, 512, 0, stream>>>(x, sidx, Wp, Sp, bl, br, CW, D,
                                                 out, XL, XR, LP);
    k_edge1<<<(NE + 255) / 256, 256, 0, stream>>>(ei, XL, XR, att, E, MORD);
    k_edge2<<<(NE + 255) / 256, 256, 0, stream>>>(ei, out, LP, E, MORD, NUM, DEN);
    k_node<<<(NSUB + 255) / 256, 256, 0, stream>>>(NUM, DEN, out);
}

// Round 2
// 69.888 us; speedup vs baseline: 1.5406x; 1.5406x over previous
//
#include <hip/hip_runtime.h>

#define NSUB   10000
#define NCLS   17
#define NG     500
#define NE     80000
#define HIDN   8
#define CWLD   52          // 0..16 = 1/Var, 17..33 = Mu/Var, 34..41 = W_l, 42..49 = W_r, 50/51 pad
#define NEG_SLOPE 0.2f
#define HALF0  248         // genes in first LDS half-tile (div 4); second half = 252

// ws layout (in floats)
#define OFF_CW   0                      // NG*CWLD = 26000
#define OFF_D    (OFF_CW + NG*CWLD)     // 32
#define OFF_XL   (OFF_D + 32)           // NSUB*8
#define OFF_XR   (OFF_XL + NSUB*HIDN)   // NSUB*8
#define OFF_LP   (OFF_XR + NSUB*HIDN)   // NSUB*17
#define OFF_E    (OFF_LP + NSUB*NCLS)   // NE
#define OFF_MORD (OFF_E + NE)           // NSUB (uint)
#define OFF_NUM  (OFF_MORD + NSUB)      // NSUB
#define OFF_DEN  (OFF_NUM + NSUB)       // NSUB

// ---------------- prep: build CW[g][52], D[c], and zero all accumulators ----------------
__global__ void k_prep(const float* __restrict__ Mu, const float* __restrict__ Var,
                       const float* __restrict__ Wl, const float* __restrict__ Wr,
                       float* __restrict__ CW, float* __restrict__ D,
                       float* __restrict__ zeroBase, float* __restrict__ out) {
    const int b = blockIdx.x;
    if (b < 2) {
        const int g = b * 256 + threadIdx.x;
        if (g < NG) {
            float* row = CW + g * CWLD;
            #pragma unroll
            for (int c = 0; c < NCLS; c++) {
                const float iv = 1.0f / Var[c * NG + g];
                row[c]        = iv;
                row[NCLS + c] = Mu[c * NG + g] * iv;
            }
            #pragma unroll
            for (int h = 0; h < HIDN; h++) {
                row[34 + h] = Wl[g * HIDN + h];
                row[42 + h] = Wr[g * HIDN + h];
            }
            row[50] = 0.f; row[51] = 0.f;
        }
    } else if (b < 19) {
        const int c = b - 2;           // 17 classes
        float s = 0.f;
        for (int g = threadIdx.x; g < NG; g += 256) {
            const float m = Mu[c * NG + g];
            s += m * m / Var[c * NG + g];
        }
        __shared__ float red[4];
        #pragma unroll
        for (int o = 32; o; o >>= 1) s += __shfl_xor(s, o);
        const int w = threadIdx.x >> 6, l = threadIdx.x & 63;
        if (l == 0) red[w] = s;
        __syncthreads();
        if (threadIdx.x == 0) D[c] = red[0] + red[1] + red[2] + red[3];
    } else {
        // zero MORD/NUM/DEN (3*NSUB contiguous floats) + out[0], out[1]
        const int i = (b - 19) * 256 + threadIdx.x;
        if (i < 3 * NSUB) zeroBase[i] = 0.f;
        if (b == 19 && threadIdx.x < 2) out[threadIdx.x] = 0.f;
    }
}

// ---------------- per-cell: LDS-staged GEMM + softmax + ll_prot + xl/xr + logP ----------------
__launch_bounds__(512)
__global__ void k_cell(const float* __restrict__ x, const int* __restrict__ sidx,
                       const float* __restrict__ Wp, const float* __restrict__ Sp,
                       const float* __restrict__ bl, const float* __restrict__ br,
                       const float* __restrict__ CW, const float* __restrict__ D,
                       float* __restrict__ out, float* __restrict__ XL,
                       float* __restrict__ XR, float* __restrict__ LP) {
    const int w = threadIdx.x >> 6, l = threadIdx.x & 63;
    const int cell = blockIdx.x * 64 + l;

    __shared__ float4 scw4[3280];          // 52.5 KB: CW half-tile, then reduce buffer
    float* scw = (float*)scw4;

    float acc[50];
    #pragma unroll
    for (int i = 0; i < 50; i++) acc[i] = 0.f;

    const bool live = (cell < NSUB);
    const float* xrow = x + (size_t)cell * NG;

    #pragma unroll 1
    for (int h = 0; h < 2; h++) {
        const int gbase = h ? HALF0 : 0;
        const int gcnt  = h ? (NG - HALF0) : HALF0;   // 248 / 252
        const float4* src = reinterpret_cast<const float4*>(CW + gbase * CWLD);
        const int n4 = gcnt * 13;
        __syncthreads();                   // previous half's reads done before overwrite
        for (int t = threadIdx.x; t < n4; t += 512) scw4[t] = src[t];
        __syncthreads();

        // per-wave gene slice within this half: waves 0..6 get 32, wave 7 gets the tail
        const int ws_start = w * 32;
        const int ws_cnt   = (w == 7) ? (gcnt - 224) : 32;   // 24 or 28 for wave 7

        if (live) {
            for (int gg = 0; gg < ws_cnt; gg += 4) {
                const float4 xv = *reinterpret_cast<const float4*>(xrow + gbase + ws_start + gg);
                #pragma unroll
                for (int j = 0; j < 4; j++) {
                    const float xs = (&xv.x)[j];
                    const float x2 = xs * xs;
                    const float4* crow = scw4 + (size_t)(ws_start + gg + j) * 13;
                    #pragma unroll
                    for (int q = 0; q < 13; q++) {
                        const float4 v = crow[q];
                        #pragma unroll
                        for (int k = 0; k < 4; k++) {
                            const int idx = q * 4 + k;
                            if (idx < 50)
                                acc[idx] += ((idx < NCLS) ? x2 : xs) * (&v.x)[k];
                        }
                    }
                }
            }
        }
    }

    // tree-reduce the 8 waves' partials (lane = cell), reusing scw (stride 51: odd → no bank conflict)
    __syncthreads();
    if (w >= 4) { float* p = scw + (size_t)((w - 4) * 64 + l) * 51;
        #pragma unroll
        for (int i = 0; i < 50; i++) p[i] = acc[i]; }
    __syncthreads();
    if (w < 4)  { const float* p = scw + (size_t)(w * 64 + l) * 51;
        #pragma unroll
        for (int i = 0; i < 50; i++) acc[i] += p[i]; }
    __syncthreads();
    if (w == 2 || w == 3) { float* p = scw + (size_t)((w - 2) * 64 + l) * 51;
        #pragma unroll
        for (int i = 0; i < 50; i++) p[i] = acc[i]; }
    __syncthreads();
    if (w < 2)  { const float* p = scw + (size_t)(w * 64 + l) * 51;
        #pragma unroll
        for (int i = 0; i < 50; i++) acc[i] += p[i]; }
    __syncthreads();
    if (w == 1) { float* p = scw + (size_t)l * 51;
        #pragma unroll
        for (int i = 0; i < 50; i++) p[i] = acc[i]; }
    __syncthreads();

    if (w == 0) {
        float ll = 0.f;
        if (live) {
            const float* p2 = scw + (size_t)l * 51;
            #pragma unroll
            for (int i = 0; i < 50; i++) acc[i] += p2[i];

            const int idx = sidx[cell];
            const float* wrow = Wp + (size_t)idx * NCLS;
            float p[NCLS];
            float mx = -1e30f;
            #pragma unroll
            for (int c = 0; c < NCLS; c++) { p[c] = wrow[c]; mx = fmaxf(mx, p[c]); }
            float sum = 0.f;
            #pragma unroll
            for (int c = 0; c < NCLS; c++) { p[c] = __expf(p[c] - mx); sum += p[c]; }
            const float inv = 1.0f / sum;
            const float s = Sp[idx];
            float* orow = out + 2 + (size_t)cell * NCLS;
            float* lrow = LP + (size_t)cell * NCLS;
            #pragma unroll
            for (int c = 0; c < NCLS; c++) {
                p[c] *= inv;
                orow[c] = p[c];
                lrow[c] = __logf(p[c] + 1e-8f);
                const float F = -0.5f * acc[c] + s * acc[NCLS + c] - 0.5f * s * s * D[c];
                ll += p[c] * F;
            }
            #pragma unroll
            for (int h = 0; h < HIDN; h++) {
                XL[cell * HIDN + h] = acc[34 + h] + bl[h];
                XR[cell * HIDN + h] = acc[42 + h] + br[h];
            }
        }
        #pragma unroll
        for (int o = 32; o; o >>= 1) ll += __shfl_xor(ll, o);
        if (l == 0) atomicAdd(out, ll * (1.0f / NSUB));
    }
}

// ---------------- edge pass 1: e_k and segment max over dst ----------------
__device__ __forceinline__ unsigned f2ord(float f) {
    unsigned u = __float_as_uint(f);
    return (u & 0x80000000u) ? ~u : (u | 0x80000000u);
}
__device__ __forceinline__ float ord2f(unsigned o) {
    unsigned u = (o & 0x80000000u) ? (o ^ 0x80000000u) : ~o;
    return __uint_as_float(u);
}

__global__ void k_edge1(const int* __restrict__ ei, const float* __restrict__ XL,
                        const float* __restrict__ XR, const float* __restrict__ att,
                        float* __restrict__ E, unsigned* __restrict__ MORD) {
    const int k = blockIdx.x * 256 + threadIdx.x;
    if (k >= NE) return;
    const int s = ei[k], d = ei[NE + k];
    const float4 a0 = *reinterpret_cast<const float4*>(XL + s * HIDN);
    const float4 a1 = *reinterpret_cast<const float4*>(XL + s * HIDN + 4);
    const float4 b0 = *reinterpret_cast<const float4*>(XR + d * HIDN);
    const float4 b1 = *reinterpret_cast<const float4*>(XR + d * HIDN + 4);
    float hv[8] = { a0.x + b0.x, a0.y + b0.y, a0.z + b0.z, a0.w + b0.w,
                    a1.x + b1.x, a1.y + b1.y, a1.z + b1.z, a1.w + b1.w };
    float e = 0.f;
    #pragma unroll
    for (int h = 0; h < HIDN; h++) {
        float v = hv[h];
        v = (v > 0.f) ? v : NEG_SLOPE * v;
        e += v * att[h];
    }
    E[k] = e;
    atomicMax(MORD + d, f2ord(e));
}

// ---------------- edge pass 2: exp + weighted accumulation ----------------
__global__ void k_edge2(const int* __restrict__ ei, const float* __restrict__ out,
                        const float* __restrict__ LP, const float* __restrict__ E,
                        const unsigned* __restrict__ MORD,
                        float* __restrict__ NUM, float* __restrict__ DEN) {
    const int k = blockIdx.x * 256 + threadIdx.x;
    if (k >= NE) return;
    const int s = ei[k], d = ei[NE + k];
    const float m = ord2f(MORD[d]);
    const float ex = __expf(E[k] - m);
    const float* Ps = out + 2 + (size_t)s * NCLS;
    const float* Ld = LP + (size_t)d * NCLS;
    float wgt = 0.f;
    #pragma unroll
    for (int c = 0; c < NCLS; c++) wgt += Ps[c] * Ld[c];
    atomicAdd(NUM + d, ex * wgt);
    atomicAdd(DEN + d, ex);
}

// ---------------- node pass: ce_space = -sum(num/den)/n ----------------
__global__ void k_node(const float* __restrict__ NUM, const float* __restrict__ DEN,
                       float* __restrict__ out) {
    const int n = blockIdx.x * 256 + threadIdx.x;
    float v = 0.f;
    if (n < NSUB) {
        const float dd = DEN[n];
        if (dd > 0.f) v = NUM[n] / dd;
    }
    #pragma unroll
    for (int o = 32; o; o >>= 1) v += __shfl_xor(v, o);
    if ((threadIdx.x & 63) == 0) atomicAdd(out + 1, -v * (1.0f / NSUB));
}

extern "C" void kernel_launch(void* const* d_in, const int* in_sizes, int n_in,
                              void* d_out, int out_size, void* d_ws, size_t ws_size,
                              hipStream_t stream) {
    const float* x    = (const float*)d_in[0];
    const float* Mu   = (const float*)d_in[1];
    const float* Var  = (const float*)d_in[2];
    const int*   ei   = (const int*)d_in[3];
    const int*   sidx = (const int*)d_in[4];
    const float* Wp   = (const float*)d_in[5];
    const float* Sp   = (const float*)d_in[6];
    const float* Wl   = (const float*)d_in[7];
    const float* bl   = (const float*)d_in[8];
    const float* Wr   = (const float*)d_in[9];
    const float* br   = (const float*)d_in[10];
    const float* att  = (const float*)d_in[11];
    float* out = (float*)d_out;
    float* ws  = (float*)d_ws;

    float*    CW   = ws + OFF_CW;
    float*    D    = ws + OFF_D;
    float*    XL   = ws + OFF_XL;
    float*    XR   = ws + OFF_XR;
    float*    LP   = ws + OFF_LP;
    float*    E    = ws + OFF_E;
    unsigned* MORD = (unsigned*)(ws + OFF_MORD);
    float*    NUM  = ws + OFF_NUM;
    float*    DEN  = ws + OFF_DEN;

    (void)in_sizes; (void)n_in; (void)out_size; (void)ws_size;

    // k_prep blocks: 2 (CW) + 17 (D) + ceil(3*NSUB/256)=118 (zeroing) => 19 + 118
    k_prep<<<19 + (3 * NSUB + 255) / 256, 256, 0, stream>>>(Mu, Var, Wl, Wr, CW, D,
                                                            ws + OFF_MORD, out);
    k_cell<<<(NSUB + 63) / 64, 512, 0, stream>>>(x, sidx, Wp, Sp, bl, br, CW, D,
                                                 out, XL, XR, LP);
    k_edge1<<<(NE + 255) / 256, 256, 0, stream>>>(ei, XL, XR, att, E, MORD);
    k_edge2<<<(NE + 255) / 256, 256, 0, stream>>>(ei, out, LP, E, MORD, NUM, DEN);
    k_node<<<(NSUB + 255) / 256, 256, 0, stream>>>(NUM, DEN, out);
}